// Round 1
// baseline (450.655 us; speedup 1.0000x reference)
//
#include <hip/hip_runtime.h>

typedef __bf16 bf16x8 __attribute__((ext_vector_type(8)));
typedef float f32x4 __attribute__((ext_vector_type(4)));

#define AS1 __attribute__((address_space(1)))
#define AS3 __attribute__((address_space(3)))

__device__ __forceinline__ unsigned short f2bf(float x) {
  unsigned int u = __float_as_uint(x);
  u += 0x7fffu + ((u >> 16) & 1u);   // RNE
  return (unsigned short)(u >> 16);
}

__device__ __forceinline__ void async_copy16(const void* g, void* l) {
  __builtin_amdgcn_global_load_lds((AS1 void*)(g), (AS3 void*)(l), 16, 0, 0);
}

// ---------------- conversions ----------------
__global__ void __launch_bounds__(256) k_conv(const float* __restrict__ s,
                                              unsigned short* __restrict__ d, int n4) {
  int i = blockIdx.x * 256 + threadIdx.x;
  if (i >= n4) return;
  float4 v = ((const float4*)s)[i];
  ushort4 o;
  o.x = f2bf(v.x); o.y = f2bf(v.y); o.z = f2bf(v.z); o.w = f2bf(v.w);
  ((ushort4*)d)[i] = o;
}

// W3 is [1000, 2048] f32 -> padded [1024, 2048] bf16 (zero rows >= 1000)
__global__ void __launch_bounds__(256) k_convw3(const float* __restrict__ s,
                                                unsigned short* __restrict__ d) {
  int i = blockIdx.x * 256 + threadIdx.x;   // i indexes float4 groups, 2048/4=512 per row
  int row = i >> 9;
  ushort4 o;
  if (row < 1000) {
    float4 v = ((const float4*)s)[i];
    o.x = f2bf(v.x); o.y = f2bf(v.y); o.z = f2bf(v.z); o.w = f2bf(v.w);
  } else {
    o.x = 0; o.y = 0; o.z = 0; o.w = 0;
  }
  ((ushort4*)d)[i] = o;
}

// ---------------- GEMM: C[M,N] = A[M,K] * B[N,K]^T (+bias), bf16 in, f32 out --------
// m97 structure: 128x128 tile, BK=32, 4 waves (2x2), 16x16x32 MFMA, global_load_lds w=16
__global__ void __launch_bounds__(256) k_gemm(const unsigned short* __restrict__ A,
                                              const unsigned short* __restrict__ B,
                                              float* __restrict__ C, int K, int ldc,
                                              int nmax, const float* __restrict__ bias) {
  __shared__ __align__(16) unsigned short lA[128 * 32];
  __shared__ __align__(16) unsigned short lB[128 * 32];
  const int tid = threadIdx.x;
  const int wave = tid >> 6;
  const int lane = tid & 63;
  const long m0 = (long)blockIdx.y * 128;
  const long n0 = (long)blockIdx.x * 128;

  // staging: each wave-instr covers 16 rows (4 lanes/row x 16B); lane i -> lds base + i*16B
  const int srow = wave * 16 + (lane >> 2);
  const int scol = (lane & 3) * 8;
  const unsigned short* ga0 = A + (m0 + srow) * (long)K + scol;
  const unsigned short* ga1 = A + (m0 + 64 + srow) * (long)K + scol;
  const unsigned short* gb0 = B + (n0 + srow) * (long)K + scol;
  const unsigned short* gb1 = B + (n0 + 64 + srow) * (long)K + scol;
  unsigned short* la0 = &lA[(wave * 16) * 32];
  unsigned short* la1 = &lA[(64 + wave * 16) * 32];
  unsigned short* lb0 = &lB[(wave * 16) * 32];
  unsigned short* lb1 = &lB[(64 + wave * 16) * 32];

  const int wr = (wave >> 1) * 64;   // wave row offset in tile
  const int wc = (wave & 1) * 64;    // wave col offset
  const int lm = lane & 15;
  const int kq = (lane >> 4) * 8;

  f32x4 acc[4][4];
#pragma unroll
  for (int i = 0; i < 4; ++i)
#pragma unroll
    for (int j = 0; j < 4; ++j) acc[i][j] = (f32x4){0.f, 0.f, 0.f, 0.f};

  for (int k0 = 0; k0 < K; k0 += 32) {
    async_copy16(ga0 + k0, la0);
    async_copy16(ga1 + k0, la1);
    async_copy16(gb0 + k0, lb0);
    async_copy16(gb1 + k0, lb1);
    __syncthreads();   // compiler inserts vmcnt(0) drain here

    bf16x8 af[4], bfr[4];
#pragma unroll
    for (int i = 0; i < 4; ++i)
      af[i] = *(const bf16x8*)&lA[(wr + i * 16 + lm) * 32 + kq];
#pragma unroll
    for (int j = 0; j < 4; ++j)
      bfr[j] = *(const bf16x8*)&lB[(wc + j * 16 + lm) * 32 + kq];
#pragma unroll
    for (int i = 0; i < 4; ++i)
#pragma unroll
      for (int j = 0; j < 4; ++j)
        acc[i][j] = __builtin_amdgcn_mfma_f32_16x16x32_bf16(af[i], bfr[j], acc[i][j], 0, 0, 0);
    __syncthreads();
  }

  // C/D layout: col = lane&15, row = (lane>>4)*4 + reg
  const int r0 = wr + (lane >> 4) * 4;
  const int c0 = wc + lm;
#pragma unroll
  for (int i = 0; i < 4; ++i) {
#pragma unroll
    for (int j = 0; j < 4; ++j) {
      int col = (int)n0 + c0 + j * 16;
      if (col < nmax) {
        float bv = bias ? bias[col] : 0.f;
#pragma unroll
        for (int r = 0; r < 4; ++r) {
          long row = m0 + r0 + i * 16 + r;
          C[row * (long)ldc + col] = acc[i][j][r] + bv;
        }
      }
    }
  }
}

// ---------------- BN column stats (8192 rows x 2048 cols) ----------------
// partial sums: 64 chunks of 128 rows. P[ch*2048+col]=sum, P[64*2048+ch*2048+col]=sumsq
__global__ void __launch_bounds__(256) k_bnpart(const float* __restrict__ Z,
                                                float* __restrict__ P) {
  int col = blockIdx.x * 256 + threadIdx.x;
  int ch = blockIdx.y;
  const float* p = Z + (long)ch * 128 * 2048 + col;
  float s = 0.f, s2 = 0.f;
#pragma unroll 4
  for (int r = 0; r < 128; ++r) {
    float v = p[(long)r * 2048];
    s += v;
    s2 = fmaf(v, v, s2);
  }
  P[ch * 2048 + col] = s;
  P[64 * 2048 + ch * 2048 + col] = s2;
}

// fold gamma/beta: h = z*scale + shift
__global__ void __launch_bounds__(256) k_bnfin(const float* __restrict__ P,
                                               const float* __restrict__ g,
                                               const float* __restrict__ be,
                                               float* __restrict__ sc,
                                               float* __restrict__ sh) {
  int col = blockIdx.x * 256 + threadIdx.x;
  float s = 0.f, s2 = 0.f;
#pragma unroll 8
  for (int ch = 0; ch < 64; ++ch) {
    s += P[ch * 2048 + col];
    s2 += P[(64 + ch) * 2048 + col];
  }
  float mean = s * (1.f / 8192.f);
  float var = s2 * (1.f / 8192.f) - mean * mean;
  float rinv = rsqrtf(var + 1e-5f);
  float a = g[col] * rinv;
  sc[col] = a;
  sh[col] = be[col] - mean * a;
}

// ---------------- fused BN-apply + relu + row-norm + hyperbolic factor + bf16 ----------
// stage 1: factor = -s * atanh(sc*dn)/(sc*dn), s=0.9*tanh(sc*n)/(sc*n), dn=max(s*n,1e-8)
__global__ void __launch_bounds__(256) k_fuse1(const float* __restrict__ Z,
                                               const float* __restrict__ sc,
                                               const float* __restrict__ sh,
                                               unsigned short* __restrict__ Ab) {
  __shared__ float red[4];
  int row = blockIdx.x, t = threadIdx.x;
  const float4* zr = (const float4*)(Z + (long)row * 2048);
  const float4* s4 = (const float4*)sc;
  const float4* h4 = (const float4*)sh;
  float4 h[2];
  float ss = 0.f;
#pragma unroll
  for (int i = 0; i < 2; ++i) {
    int c = t + i * 256;
    float4 z = zr[c], a = s4[c], b = h4[c];
    float4 v;
    v.x = fmaxf(fmaf(z.x, a.x, b.x), 0.f);
    v.y = fmaxf(fmaf(z.y, a.y, b.y), 0.f);
    v.z = fmaxf(fmaf(z.z, a.z, b.z), 0.f);
    v.w = fmaxf(fmaf(z.w, a.w, b.w), 0.f);
    ss += v.x * v.x + v.y * v.y + v.z * v.z + v.w * v.w;
    h[i] = v;
  }
#pragma unroll
  for (int o = 32; o > 0; o >>= 1) ss += __shfl_down(ss, o, 64);
  if ((t & 63) == 0) red[t >> 6] = ss;
  __syncthreads();
  float n2 = red[0] + red[1] + red[2] + red[3];

  float fac = 0.f;
  if (n2 > 0.f) {
    const float rsc = 0.31622776601683794f;  // sqrt(0.1)
    float n = sqrtf(n2);
    float th = tanhf(rsc * n);
    float s = 0.9f * th / (rsc * n);
    float dn = fmaxf(s * n, 1e-8f);
    float z = rsc * dn;
    fac = -(atanhf(z) / z) * s;
  }
  ushort4* dr = (ushort4*)(Ab + (long)row * 2048);
#pragma unroll
  for (int i = 0; i < 2; ++i) {
    int c = t + i * 256;
    float4 v = h[i];
    ushort4 o;
    o.x = f2bf(v.x * fac); o.y = f2bf(v.y * fac);
    o.z = f2bf(v.z * fac); o.w = f2bf(v.w * fac);
    dr[c] = o;
  }
}

// stage 2: exp-map at origin + poincare->euclidean: factor = scl * atanh(sc*cn)/(sc*cn)
__global__ void __launch_bounds__(256) k_fuse2(const float* __restrict__ Z,
                                               const float* __restrict__ sc,
                                               const float* __restrict__ sh,
                                               unsigned short* __restrict__ Ab) {
  __shared__ float red[4];
  int row = blockIdx.x, t = threadIdx.x;
  const float4* zr = (const float4*)(Z + (long)row * 2048);
  const float4* s4 = (const float4*)sc;
  const float4* h4 = (const float4*)sh;
  float4 h[2];
  float ss = 0.f;
#pragma unroll
  for (int i = 0; i < 2; ++i) {
    int c = t + i * 256;
    float4 z = zr[c], a = s4[c], b = h4[c];
    float4 v;
    v.x = fmaxf(fmaf(z.x, a.x, b.x), 0.f);
    v.y = fmaxf(fmaf(z.y, a.y, b.y), 0.f);
    v.z = fmaxf(fmaf(z.z, a.z, b.z), 0.f);
    v.w = fmaxf(fmaf(z.w, a.w, b.w), 0.f);
    ss += v.x * v.x + v.y * v.y + v.z * v.z + v.w * v.w;
    h[i] = v;
  }
#pragma unroll
  for (int o = 32; o > 0; o >>= 1) ss += __shfl_down(ss, o, 64);
  if ((t & 63) == 0) red[t >> 6] = ss;
  __syncthreads();
  float n2 = red[0] + red[1] + red[2] + red[3];

  const float rsc = 0.31622776601683794f;
  float nn = sqrtf(n2);
  float vn = fmaxf(nn, 1e-8f);
  float tt = rsc * vn;
  float scl = tanhf(tt) / tt;                       // tanh(sc*vn)/(sc*vn)
  float hn = scl * nn;                              // ||h2_hyp||
  float cn = fminf(fmaxf(hn, 1e-8f), 1.0f);         // clip (1-1e-8 == 1.0f in fp32)
  float z = rsc * cn;
  float fac = scl * (atanhf(z) / z);

  ushort4* dr = (ushort4*)(Ab + (long)row * 2048);
#pragma unroll
  for (int i = 0; i < 2; ++i) {
    int c = t + i * 256;
    float4 v = h[i];
    ushort4 o;
    o.x = f2bf(v.x * fac); o.y = f2bf(v.y * fac);
    o.z = f2bf(v.z * fac); o.w = f2bf(v.w * fac);
    dr[c] = o;
  }
}

// ---------------- log_softmax over 1000 cols ----------------
__global__ void __launch_bounds__(256) k_lsm(const float* __restrict__ Z,
                                             float* __restrict__ out) {
  __shared__ float red[4];
  int row = blockIdx.x, t = threadIdx.x;
  const float* zr = Z + (long)row * 1000;
  float v[4];
  float mx = -3.4e38f;
#pragma unroll
  for (int i = 0; i < 4; ++i) {
    int c = t + i * 256;
    v[i] = (c < 1000) ? zr[c] : -3.4e38f;
    mx = fmaxf(mx, v[i]);
  }
#pragma unroll
  for (int o = 32; o > 0; o >>= 1) mx = fmaxf(mx, __shfl_down(mx, o, 64));
  if ((t & 63) == 0) red[t >> 6] = mx;
  __syncthreads();
  mx = fmaxf(fmaxf(red[0], red[1]), fmaxf(red[2], red[3]));
  __syncthreads();

  float se = 0.f;
#pragma unroll
  for (int i = 0; i < 4; ++i) {
    int c = t + i * 256;
    if (c < 1000) se += expf(v[i] - mx);
  }
#pragma unroll
  for (int o = 32; o > 0; o >>= 1) se += __shfl_down(se, o, 64);
  if ((t & 63) == 0) red[t >> 6] = se;
  __syncthreads();
  float s = red[0] + red[1] + red[2] + red[3];
  float ls = logf(s);
#pragma unroll
  for (int i = 0; i < 4; ++i) {
    int c = t + i * 256;
    if (c < 1000) out[(long)row * 1000 + c] = v[i] - mx - ls;
  }
}

extern "C" void kernel_launch(void* const* d_in, const int* in_sizes, int n_in,
                              void* d_out, int out_size, void* d_ws, size_t ws_size,
                              hipStream_t stream) {
  (void)in_sizes; (void)n_in; (void)out_size; (void)ws_size;
  const float* x   = (const float*)d_in[0];
  const float* W1  = (const float*)d_in[1];
  // d_in[2] = b1: exactly cancelled by BN (mean absorbs it) -> skipped
  const float* g1  = (const float*)d_in[3];
  const float* be1 = (const float*)d_in[4];
  const float* W2  = (const float*)d_in[5];
  // d_in[6] = b2: cancelled by BN
  const float* g2  = (const float*)d_in[7];
  const float* be2 = (const float*)d_in[8];
  const float* W3  = (const float*)d_in[9];
  const float* b3  = (const float*)d_in[10];
  float* out = (float*)d_out;

  char* ws = (char*)d_ws;
  size_t off = 0;
  auto alloc = [&](size_t bytes) {
    void* p = ws + off;
    off += (bytes + 255) & ~(size_t)255;
    return p;
  };
  unsigned short* Xb  = (unsigned short*)alloc((size_t)8192 * 1024 * 2);
  unsigned short* W1b = (unsigned short*)alloc((size_t)2048 * 1024 * 2);
  unsigned short* W2b = (unsigned short*)alloc((size_t)2048 * 2048 * 2);
  unsigned short* W3b = (unsigned short*)alloc((size_t)1024 * 2048 * 2);
  float* Z            = (float*)alloc((size_t)8192 * 2048 * 4);
  unsigned short* Ab  = (unsigned short*)alloc((size_t)8192 * 2048 * 2);
  float* P            = (float*)alloc((size_t)2 * 64 * 2048 * 4);
  float* SC           = (float*)alloc(2048 * 4);
  float* SH           = (float*)alloc(2048 * 4);

  // bf16 conversions
  k_conv<<<8192, 256, 0, stream>>>(x, Xb, 8192 * 1024 / 4);
  k_conv<<<2048, 256, 0, stream>>>(W1, W1b, 2048 * 1024 / 4);
  k_conv<<<4096, 256, 0, stream>>>(W2, W2b, 2048 * 2048 / 4);
  k_convw3<<<2048, 256, 0, stream>>>(W3, W3b);

  // layer 1
  k_gemm<<<dim3(16, 64), 256, 0, stream>>>(Xb, W1b, Z, 1024, 2048, 2048, nullptr);
  k_bnpart<<<dim3(8, 64), 256, 0, stream>>>(Z, P);
  k_bnfin<<<8, 256, 0, stream>>>(P, g1, be1, SC, SH);
  k_fuse1<<<8192, 256, 0, stream>>>(Z, SC, SH, Ab);

  // layer 2
  k_gemm<<<dim3(16, 64), 256, 0, stream>>>(Ab, W2b, Z, 2048, 2048, 2048, nullptr);
  k_bnpart<<<dim3(8, 64), 256, 0, stream>>>(Z, P);
  k_bnfin<<<8, 256, 0, stream>>>(P, g2, be2, SC, SH);
  k_fuse2<<<8192, 256, 0, stream>>>(Z, SC, SH, Ab);

  // layer 3 + log_softmax
  k_gemm<<<dim3(8, 64), 256, 0, stream>>>(Ab, W3b, Z, 2048, 1000, 1000, b3);
  k_lsm<<<8192, 256, 0, stream>>>(Z, out);
}

// Round 2
// 376.246 us; speedup vs baseline: 1.1978x; 1.1978x over previous
//
#include <hip/hip_runtime.h>

typedef __bf16 bf16x8 __attribute__((ext_vector_type(8)));
typedef float f32x4 __attribute__((ext_vector_type(4)));
typedef unsigned short us8 __attribute__((ext_vector_type(8)));

#define AS1 __attribute__((address_space(1)))
#define AS3 __attribute__((address_space(3)))

__device__ __forceinline__ unsigned short f2bf(float x) {
  unsigned int u = __float_as_uint(x);
  u += 0x7fffu + ((u >> 16) & 1u);   // RNE
  return (unsigned short)(u >> 16);
}
__device__ __forceinline__ float bf2f(unsigned short u) {
  return __uint_as_float(((unsigned int)u) << 16);
}
__device__ __forceinline__ void async_copy16(const void* g, void* l) {
  __builtin_amdgcn_global_load_lds((AS1 void*)(g), (AS3 void*)(l), 16, 0, 0);
}

// ------------- prep: all f32->bf16 conversions + P zeroing, one launch -------------
__global__ void __launch_bounds__(256) k_prep(const float* __restrict__ x,
                                              const float* __restrict__ W1,
                                              const float* __restrict__ W2,
                                              const float* __restrict__ W3,
                                              unsigned short* __restrict__ Xb,
                                              unsigned short* __restrict__ W1b,
                                              unsigned short* __restrict__ W2b,
                                              unsigned short* __restrict__ W3b,
                                              float* __restrict__ P) {
  const long n1 = 2097152, n2 = 524288, n3 = 1048576, n4 = 524288;
  long i = (long)blockIdx.x * 256 + threadIdx.x;   // float4 group index
  const float* s = nullptr;
  unsigned short* d = nullptr;
  long j = i;
  if (i < n1)                { s = x;  d = Xb; }
  else if ((j -= n1) < n2)   { s = W1; d = W1b; }
  else if ((j -= n2) < n3)   { s = W2; d = W2b; }
  else if ((j -= n3) < n4) {
    // W3: [1000,2048] -> padded [1024,2048], zero rows >= 1000
    ushort4 o;
    if ((j >> 9) < 1000) {
      float4 v = ((const float4*)W3)[j];
      o.x = f2bf(v.x); o.y = f2bf(v.y); o.z = f2bf(v.z); o.w = f2bf(v.w);
    } else { o.x = 0; o.y = 0; o.z = 0; o.w = 0; }
    ((ushort4*)W3b)[j] = o;
    return;
  } else {
    j -= n4;                                        // 0..2047 -> zero P (2 buffers)
    ((float4*)P)[j] = (float4){0.f, 0.f, 0.f, 0.f};
    return;
  }
  float4 v = ((const float4*)s)[j];
  ushort4 o;
  o.x = f2bf(v.x); o.y = f2bf(v.y); o.z = f2bf(v.z); o.w = f2bf(v.w);
  ((ushort4*)d)[j] = o;
}

// ---------------- GEMM: C[M,N] = A[M,K] * B[N,K]^T (+bias), bf16 in ----------------
// 128x128 tile, BK=64 (32 MFMA per barrier-pair), XOR-swizzled LDS chunks so the
// 128B row stride doesn't alias banks. global_load_lds w=16 staging.
// STATS: accumulate per-column sum/sumsq of C into P[0..2047]/P[2048..4095] (atomics).
template <bool OUTBF16, bool STATS>
__global__ void __launch_bounds__(256) k_gemm(const unsigned short* __restrict__ A,
                                              const unsigned short* __restrict__ B,
                                              void* __restrict__ Cout, int K, int ldc,
                                              int nmax, const float* __restrict__ bias,
                                              float* __restrict__ P) {
  __shared__ __align__(16) unsigned short lA[128 * 64];
  __shared__ __align__(16) unsigned short lB[128 * 64];
  const int tid = threadIdx.x;
  const int wave = tid >> 6;
  const int lane = tid & 63;
  const long m0 = (long)blockIdx.y * 128;
  const long n0 = (long)blockIdx.x * 128;

  // staging: wave covers rows [wave*32, wave*32+32) of each tile, 4 rounds of 8 rows.
  // LDS slot (row, pos) gets global chunk (pos ^ (row&7)); lane l -> row l>>3, pos l&7.
  const int rsub = lane >> 3;                     // 0..7
  const int qg = ((lane & 7) ^ rsub) * 8;         // swizzled global chunk, in halves
  const unsigned short* gA = A + (m0 + wave * 32 + rsub) * (long)K + qg;
  const unsigned short* gB = B + (n0 + wave * 32 + rsub) * (long)K + qg;
  unsigned short* lAw = lA + (wave * 32) * 64;
  unsigned short* lBw = lB + (wave * 32) * 64;

  const int wr = (wave >> 1) * 64;                // wave row offset in tile
  const int wc = (wave & 1) * 64;                 // wave col offset
  const int lm = lane & 15;
  const int quad = lane >> 4;
  const int sw = lm & 7;                          // row&7 for all fragment rows
  const int o0 = (quad ^ sw) * 8;                 // k-step 0 chunk offset (halves)
  const int o1 = ((quad + 4) ^ sw) * 8;           // k-step 1

  f32x4 acc[4][4];
#pragma unroll
  for (int i = 0; i < 4; ++i)
#pragma unroll
    for (int j = 0; j < 4; ++j) acc[i][j] = (f32x4){0.f, 0.f, 0.f, 0.f};

  for (int k0 = 0; k0 < K; k0 += 64) {
#pragma unroll
    for (int r = 0; r < 4; ++r) {
      async_copy16(gA + (long)(r * 8) * K + k0, lAw + r * 8 * 64);
      async_copy16(gB + (long)(r * 8) * K + k0, lBw + r * 8 * 64);
    }
    __syncthreads();

    bf16x8 af[4], bfr[4];
#pragma unroll
    for (int i = 0; i < 4; ++i)
      af[i] = *(const bf16x8*)&lA[(wr + i * 16 + lm) * 64 + o0];
#pragma unroll
    for (int j = 0; j < 4; ++j)
      bfr[j] = *(const bf16x8*)&lB[(wc + j * 16 + lm) * 64 + o0];
#pragma unroll
    for (int i = 0; i < 4; ++i)
#pragma unroll
      for (int j = 0; j < 4; ++j)
        acc[i][j] = __builtin_amdgcn_mfma_f32_16x16x32_bf16(af[i], bfr[j], acc[i][j], 0, 0, 0);

#pragma unroll
    for (int i = 0; i < 4; ++i)
      af[i] = *(const bf16x8*)&lA[(wr + i * 16 + lm) * 64 + o1];
#pragma unroll
    for (int j = 0; j < 4; ++j)
      bfr[j] = *(const bf16x8*)&lB[(wc + j * 16 + lm) * 64 + o1];
#pragma unroll
    for (int i = 0; i < 4; ++i)
#pragma unroll
      for (int j = 0; j < 4; ++j)
        acc[i][j] = __builtin_amdgcn_mfma_f32_16x16x32_bf16(af[i], bfr[j], acc[i][j], 0, 0, 0);
    __syncthreads();
  }

  // C/D layout: col = lane&15, row = quad*4 + reg
  const int r0 = wr + quad * 4;
  const int c0 = wc + lm;
  if (OUTBF16) {
    unsigned short* C = (unsigned short*)Cout;
#pragma unroll
    for (int i = 0; i < 4; ++i)
#pragma unroll
      for (int j = 0; j < 4; ++j) {
        int col = (int)n0 + c0 + j * 16;
#pragma unroll
        for (int r = 0; r < 4; ++r)
          C[(m0 + r0 + i * 16 + r) * (long)ldc + col] = f2bf(acc[i][j][r]);
      }
  } else {
    float* C = (float*)Cout;
#pragma unroll
    for (int i = 0; i < 4; ++i)
#pragma unroll
      for (int j = 0; j < 4; ++j) {
        int col = (int)n0 + c0 + j * 16;
        if (col < nmax) {
          float bv = bias ? bias[col] : 0.f;
#pragma unroll
          for (int r = 0; r < 4; ++r)
            C[(m0 + r0 + i * 16 + r) * (long)ldc + col] = acc[i][j][r] + bv;
        }
      }
  }

  if (STATS) {
    float* sred = (float*)lA;    // reuse LDS (post final barrier)
    sred[tid] = 0.f;             // 256 floats: sum[0..127], sumsq[128..255]
    __syncthreads();
#pragma unroll
    for (int j = 0; j < 4; ++j) {
      float s = 0.f, s2 = 0.f;
#pragma unroll
      for (int i = 0; i < 4; ++i)
#pragma unroll
        for (int r = 0; r < 4; ++r) {
          float v = acc[i][j][r];
          s += v;
          s2 = fmaf(v, v, s2);
        }
      int cl = c0 + j * 16;      // 0..127
      atomicAdd(&sred[cl], s);
      atomicAdd(&sred[128 + cl], s2);
    }
    __syncthreads();
    if (tid < 128) {
      atomicAdd(&P[n0 + tid], sred[tid]);
      atomicAdd(&P[2048 + n0 + tid], sred[128 + tid]);
    }
  }
}

// ---------------- BN finalize: fold gamma/beta into per-col scale/shift ------------
__global__ void __launch_bounds__(256) k_bnfin(const float* __restrict__ P,
                                               const float* __restrict__ g,
                                               const float* __restrict__ be,
                                               float* __restrict__ sc,
                                               float* __restrict__ sh) {
  int col = blockIdx.x * 256 + threadIdx.x;
  float mean = P[col] * (1.f / 8192.f);
  float var = P[2048 + col] * (1.f / 8192.f) - mean * mean;
  float rinv = rsqrtf(var + 1e-5f);
  float a = g[col] * rinv;
  sc[col] = a;
  sh[col] = be[col] - mean * a;
}

// ------- fused BN-apply + relu + row-norm + hyperbolic per-row factor + bf16 -------
// STAGE2=false: factor = -s * atanh(rsc*dn)/(rsc*dn), s = 0.9*tanh(rsc*n)/(rsc*n)
// STAGE2=true:  factor = scl * atanh(rsc*cn)/(rsc*cn), scl = tanh(rsc*vn)/(rsc*vn)
template <bool STAGE2>
__global__ void __launch_bounds__(256) k_fuse(const unsigned short* __restrict__ Zb,
                                              const float* __restrict__ sc,
                                              const float* __restrict__ sh,
                                              unsigned short* __restrict__ Ab) {
  __shared__ float red[4];
  int row = blockIdx.x, t = threadIdx.x;
  us8 z8 = ((const us8*)(Zb + (long)row * 2048))[t];
  float4 a0 = ((const float4*)sc)[2 * t], a1 = ((const float4*)sc)[2 * t + 1];
  float4 b0 = ((const float4*)sh)[2 * t], b1 = ((const float4*)sh)[2 * t + 1];
  float v[8];
  v[0] = fmaxf(fmaf(bf2f(z8[0]), a0.x, b0.x), 0.f);
  v[1] = fmaxf(fmaf(bf2f(z8[1]), a0.y, b0.y), 0.f);
  v[2] = fmaxf(fmaf(bf2f(z8[2]), a0.z, b0.z), 0.f);
  v[3] = fmaxf(fmaf(bf2f(z8[3]), a0.w, b0.w), 0.f);
  v[4] = fmaxf(fmaf(bf2f(z8[4]), a1.x, b1.x), 0.f);
  v[5] = fmaxf(fmaf(bf2f(z8[5]), a1.y, b1.y), 0.f);
  v[6] = fmaxf(fmaf(bf2f(z8[6]), a1.z, b1.z), 0.f);
  v[7] = fmaxf(fmaf(bf2f(z8[7]), a1.w, b1.w), 0.f);
  float ss = 0.f;
#pragma unroll
  for (int i = 0; i < 8; ++i) ss = fmaf(v[i], v[i], ss);
#pragma unroll
  for (int o = 32; o > 0; o >>= 1) ss += __shfl_down(ss, o, 64);
  if ((t & 63) == 0) red[t >> 6] = ss;
  __syncthreads();
  float n2 = red[0] + red[1] + red[2] + red[3];

  const float rsc = 0.31622776601683794f;  // sqrt(0.1)
  float fac;
  if (STAGE2) {
    float nn = sqrtf(n2);
    float vn = fmaxf(nn, 1e-8f);
    float tt = rsc * vn;
    float scl = tanhf(tt) / tt;
    float hn = scl * nn;
    float cn = fminf(fmaxf(hn, 1e-8f), 1.0f);
    float z = rsc * cn;
    fac = scl * (atanhf(z) / z);
  } else {
    fac = 0.f;
    if (n2 > 0.f) {
      float n = sqrtf(n2);
      float th = tanhf(rsc * n);
      float s = 0.9f * th / (rsc * n);
      float dn = fmaxf(s * n, 1e-8f);
      float z = rsc * dn;
      fac = -(atanhf(z) / z) * s;
    }
  }
  us8 o8;
#pragma unroll
  for (int i = 0; i < 8; ++i) o8[i] = f2bf(v[i] * fac);
  ((us8*)(Ab + (long)row * 2048))[t] = o8;
}

// ---------------- log_softmax over 1000 cols ----------------
__global__ void __launch_bounds__(256) k_lsm(const float* __restrict__ Z,
                                             float* __restrict__ out) {
  __shared__ float red[4];
  int row = blockIdx.x, t = threadIdx.x;
  const float* zr = Z + (long)row * 1000;
  float v[4];
  float mx = -3.4e38f;
#pragma unroll
  for (int i = 0; i < 4; ++i) {
    int c = t + i * 256;
    v[i] = (c < 1000) ? zr[c] : -3.4e38f;
    mx = fmaxf(mx, v[i]);
  }
#pragma unroll
  for (int o = 32; o > 0; o >>= 1) mx = fmaxf(mx, __shfl_down(mx, o, 64));
  if ((t & 63) == 0) red[t >> 6] = mx;
  __syncthreads();
  mx = fmaxf(fmaxf(red[0], red[1]), fmaxf(red[2], red[3]));
  __syncthreads();

  float se = 0.f;
#pragma unroll
  for (int i = 0; i < 4; ++i) {
    int c = t + i * 256;
    if (c < 1000) se += expf(v[i] - mx);
  }
#pragma unroll
  for (int o = 32; o > 0; o >>= 1) se += __shfl_down(se, o, 64);
  if ((t & 63) == 0) red[t >> 6] = se;
  __syncthreads();
  float s = red[0] + red[1] + red[2] + red[3];
  float ls = logf(s);
#pragma unroll
  for (int i = 0; i < 4; ++i) {
    int c = t + i * 256;
    if (c < 1000) out[(long)row * 1000 + c] = v[i] - mx - ls;
  }
}

extern "C" void kernel_launch(void* const* d_in, const int* in_sizes, int n_in,
                              void* d_out, int out_size, void* d_ws, size_t ws_size,
                              hipStream_t stream) {
  (void)in_sizes; (void)n_in; (void)out_size; (void)ws_size;
  const float* x   = (const float*)d_in[0];
  const float* W1  = (const float*)d_in[1];
  // d_in[2] = b1: exactly cancelled by BN (mean absorbs it)
  const float* g1  = (const float*)d_in[3];
  const float* be1 = (const float*)d_in[4];
  const float* W2  = (const float*)d_in[5];
  // d_in[6] = b2: cancelled by BN
  const float* g2  = (const float*)d_in[7];
  const float* be2 = (const float*)d_in[8];
  const float* W3  = (const float*)d_in[9];
  const float* b3  = (const float*)d_in[10];
  float* out = (float*)d_out;

  char* ws = (char*)d_ws;
  size_t off = 0;
  auto alloc = [&](size_t bytes) {
    void* p = ws + off;
    off += (bytes + 255) & ~(size_t)255;
    return p;
  };
  unsigned short* Xb  = (unsigned short*)alloc((size_t)8192 * 1024 * 2);
  unsigned short* W1b = (unsigned short*)alloc((size_t)2048 * 1024 * 2);
  unsigned short* W2b = (unsigned short*)alloc((size_t)2048 * 2048 * 2);
  unsigned short* W3b = (unsigned short*)alloc((size_t)1024 * 2048 * 2);
  unsigned short* Zb  = (unsigned short*)alloc((size_t)8192 * 2048 * 2);
  unsigned short* Ab  = (unsigned short*)alloc((size_t)8192 * 2048 * 2);
  float* Z3           = (float*)alloc((size_t)8192 * 1000 * 4);
  float* P            = (float*)alloc((size_t)2 * 4096 * 4);   // P1 | P2, zeroed by k_prep
  float* SC           = (float*)alloc(2048 * 4);
  float* SH           = (float*)alloc(2048 * 4);
  float* P2 = P + 4096;

  // conversions + P zeroing: (2097152+524288+1048576+524288+2048)/256 = 16392 blocks
  k_prep<<<16392, 256, 0, stream>>>(x, W1, W2, W3, Xb, W1b, W2b, W3b, P);

  // layer 1: GEMM (+BN stats) -> bnfin -> fused hyperbolic
  k_gemm<true, true><<<dim3(16, 64), 256, 0, stream>>>(Xb, W1b, Zb, 1024, 2048, 2048, nullptr, P);
  k_bnfin<<<8, 256, 0, stream>>>(P, g1, be1, SC, SH);
  k_fuse<false><<<8192, 256, 0, stream>>>(Zb, SC, SH, Ab);

  // layer 2
  k_gemm<true, true><<<dim3(16, 64), 256, 0, stream>>>(Ab, W2b, Zb, 2048, 2048, 2048, nullptr, P2);
  k_bnfin<<<8, 256, 0, stream>>>(P2, g2, be2, SC, SH);
  k_fuse<true><<<8192, 256, 0, stream>>>(Zb, SC, SH, Ab);

  // layer 3 + log_softmax
  k_gemm<false, false><<<dim3(8, 64), 256, 0, stream>>>(Ab, W3b, Z3, 2048, 1000, 1000, b3, nullptr);
  k_lsm<<<8192, 256, 0, stream>>>(Z3, out);
}

// Round 4
// 361.036 us; speedup vs baseline: 1.2482x; 1.0421x over previous
//
#include <hip/hip_runtime.h>

typedef __bf16 bf16x8 __attribute__((ext_vector_type(8)));
typedef float f32x16 __attribute__((ext_vector_type(16)));
typedef unsigned short us8 __attribute__((ext_vector_type(8)));

#define AS1 __attribute__((address_space(1)))
#define AS3 __attribute__((address_space(3)))

__device__ __forceinline__ unsigned short f2bf(float x) {
  unsigned int u = __float_as_uint(x);
  u += 0x7fffu + ((u >> 16) & 1u);   // RNE
  return (unsigned short)(u >> 16);
}
__device__ __forceinline__ float bf2f(unsigned short u) {
  return __uint_as_float(((unsigned int)u) << 16);
}
__device__ __forceinline__ void async_copy16(const void* g, void* l) {
  __builtin_amdgcn_global_load_lds((AS1 void*)(g), (AS3 void*)(l), 16, 0, 0);
}

// ------------- prep: all f32->bf16 conversions + P zeroing, one launch -------------
__global__ void __launch_bounds__(256) k_prep(const float* __restrict__ x,
                                              const float* __restrict__ W1,
                                              const float* __restrict__ W2,
                                              const float* __restrict__ W3,
                                              unsigned short* __restrict__ Xb,
                                              unsigned short* __restrict__ W1b,
                                              unsigned short* __restrict__ W2b,
                                              unsigned short* __restrict__ W3b,
                                              float* __restrict__ P) {
  const long n1 = 2097152, n2 = 524288, n3 = 1048576, n4 = 524288;
  long i = (long)blockIdx.x * 256 + threadIdx.x;   // float4 group index
  const float* s = nullptr;
  unsigned short* d = nullptr;
  long j = i;
  if (i < n1)                { s = x;  d = Xb; }
  else if ((j -= n1) < n2)   { s = W1; d = W1b; }
  else if ((j -= n2) < n3)   { s = W2; d = W2b; }
  else if ((j -= n3) < n4) {
    // W3: [1000,2048] -> padded [1024,2048], zero rows >= 1000
    ushort4 o;
    if ((j >> 9) < 1000) {
      float4 v = ((const float4*)W3)[j];
      o.x = f2bf(v.x); o.y = f2bf(v.y); o.z = f2bf(v.z); o.w = f2bf(v.w);
    } else { o.x = 0; o.y = 0; o.z = 0; o.w = 0; }
    ((ushort4*)W3b)[j] = o;
    return;
  } else {
    j -= n4;                                        // 0..2047 -> zero P (2 buffers)
    ((float4*)P)[j] = (float4){0.f, 0.f, 0.f, 0.f};
    return;
  }
  float4 v = ((const float4*)s)[j];
  ushort4 o;
  o.x = f2bf(v.x); o.y = f2bf(v.y); o.z = f2bf(v.z); o.w = f2bf(v.w);
  ((ushort4*)d)[j] = o;
}

// ---------------- GEMM: C[M,N] = A[M,K] * B[N,K]^T, bf16 in -----------------------
// 128x128 tile, BK=64, 32x32x16 MFMA core (16 MFMA / 16 ds_read_b128 per iter),
// XOR chunk swizzle (conflict-free), global_load_lds w=16 staging.
// STATS: per-column sum/sumsq of C atomically into P[0..2047]/P[2048..4095].
template <bool OUTBF16, bool STATS>
__global__ void __launch_bounds__(256) k_gemm(const unsigned short* __restrict__ A,
                                              const unsigned short* __restrict__ B,
                                              void* __restrict__ Cout, int K,
                                              int lda, int ldb, int ldc, int nmax,
                                              const float* __restrict__ bias,
                                              float* __restrict__ P) {
  __shared__ __align__(16) unsigned short lA[128 * 64];
  __shared__ __align__(16) unsigned short lB[128 * 64];
  const int tid = threadIdx.x;
  const int wave = tid >> 6;
  const int lane = tid & 63;
  const long m0 = (long)blockIdx.y * 128;
  const long n0 = (long)blockIdx.x * 128;

  // staging: wave covers rows [wave*32, wave*32+32), 4 rounds of 8 rows.
  // LDS slot (row, pos) holds global chunk (pos ^ (row&7)); lane l -> row l>>3, pos l&7.
  const int rsub = lane >> 3;                     // 0..7
  const int qg = ((lane & 7) ^ rsub) * 8;         // swizzled global chunk (halves)
  const unsigned short* gA = A + (m0 + wave * 32 + rsub) * (long)lda + qg;
  const unsigned short* gB = B + (n0 + wave * 32 + rsub) * (long)ldb + qg;
  unsigned short* lAw = lA + (wave * 32) * 64;
  unsigned short* lBw = lB + (wave * 32) * 64;

  const int wr = (wave >> 1) * 64;                // wave row offset in tile
  const int wc = (wave & 1) * 64;                 // wave col offset
  const int l31 = lane & 31;
  const int khalf = lane >> 5;                    // 0..1
  const int r7 = l31 & 7;                         // fragment row & 7 (swizzle key)

  f32x16 acc[2][2];
#pragma unroll
  for (int i = 0; i < 2; ++i)
#pragma unroll
    for (int j = 0; j < 2; ++j) acc[i][j] = (f32x16)(0.f);

  for (int k0 = 0; k0 < K; k0 += 64) {
#pragma unroll
    for (int r = 0; r < 4; ++r) {
      async_copy16(gA + (long)(r * 8) * lda + k0, lAw + r * 8 * 64);
      async_copy16(gB + (long)(r * 8) * ldb + k0, lBw + r * 8 * 64);
    }
    __syncthreads();

#pragma unroll
    for (int ks = 0; ks < 4; ++ks) {             // K-step of 16
      const int off = ((ks * 2 + khalf) ^ r7) * 8;
      bf16x8 af[2], bfr[2];
#pragma unroll
      for (int i = 0; i < 2; ++i)
        af[i] = *(const bf16x8*)&lA[(wr + i * 32 + l31) * 64 + off];
#pragma unroll
      for (int j = 0; j < 2; ++j)
        bfr[j] = *(const bf16x8*)&lB[(wc + j * 32 + l31) * 64 + off];
#pragma unroll
      for (int i = 0; i < 2; ++i)
#pragma unroll
        for (int j = 0; j < 2; ++j)
          acc[i][j] = __builtin_amdgcn_mfma_f32_32x32x16_bf16(af[i], bfr[j], acc[i][j], 0, 0, 0);
    }
    __syncthreads();
  }

  // C/D layout: col = lane&31, row = (reg&3) + 8*(reg>>2) + 4*(lane>>5)
  const int rbase = 4 * khalf;
  if (OUTBF16) {
    unsigned short* C = (unsigned short*)Cout;
#pragma unroll
    for (int i = 0; i < 2; ++i)
#pragma unroll
      for (int j = 0; j < 2; ++j) {
        long col = n0 + wc + j * 32 + l31;
#pragma unroll
        for (int reg = 0; reg < 16; ++reg) {
          long row = m0 + wr + i * 32 + (reg & 3) + 8 * (reg >> 2) + rbase;
          C[row * (long)ldc + col] = f2bf(acc[i][j][reg]);
        }
      }
  } else {
    float* C = (float*)Cout;
#pragma unroll
    for (int i = 0; i < 2; ++i)
#pragma unroll
      for (int j = 0; j < 2; ++j) {
        long col = n0 + wc + j * 32 + l31;
        if (col < nmax) {
          float bv = bias ? bias[col] : 0.f;
#pragma unroll
          for (int reg = 0; reg < 16; ++reg) {
            long row = m0 + wr + i * 32 + (reg & 3) + 8 * (reg >> 2) + rbase;
            C[row * (long)ldc + col] = acc[i][j][reg] + bv;
          }
        }
      }
  }

  if (STATS) {
    float* sred = (float*)lA;    // reuse LDS (post final barrier)
    sred[tid] = 0.f;             // sum[0..127], sumsq[128..255]
    __syncthreads();
#pragma unroll
    for (int j = 0; j < 2; ++j) {
      float s = 0.f, s2 = 0.f;
#pragma unroll
      for (int i = 0; i < 2; ++i)
#pragma unroll
        for (int reg = 0; reg < 16; ++reg) {
          float v = acc[i][j][reg];
          s += v;
          s2 = fmaf(v, v, s2);
        }
      int cl = wc + j * 32 + l31;      // 0..127
      atomicAdd(&sred[cl], s);
      atomicAdd(&sred[128 + cl], s2);
    }
    __syncthreads();
    if (tid < 128) {
      atomicAdd(&P[n0 + tid], sred[tid]);
      atomicAdd(&P[2048 + n0 + tid], sred[128 + tid]);
    }
  }
}

// ---------------- BN finalize: fold gamma/beta into per-col scale/shift ------------
__global__ void __launch_bounds__(256) k_bnfin(const float* __restrict__ P,
                                               const float* __restrict__ g,
                                               const float* __restrict__ be,
                                               float* __restrict__ sc,
                                               float* __restrict__ sh) {
  int col = blockIdx.x * 256 + threadIdx.x;
  float mean = P[col] * (1.f / 8192.f);
  float var = P[2048 + col] * (1.f / 8192.f) - mean * mean;
  float rinv = rsqrtf(var + 1e-5f);
  float a = g[col] * rinv;
  sc[col] = a;
  sh[col] = be[col] - mean * a;
}

// ------- fused BN-apply + relu + row-norm + hyperbolic per-row factor + bf16 -------
template <bool STAGE2>
__global__ void __launch_bounds__(256) k_fuse(const unsigned short* __restrict__ Zb,
                                              const float* __restrict__ sc,
                                              const float* __restrict__ sh,
                                              unsigned short* __restrict__ Ab) {
  __shared__ float red[4];
  int row = blockIdx.x, t = threadIdx.x;
  us8 z8 = ((const us8*)(Zb + (long)row * 2048))[t];
  float4 a0 = ((const float4*)sc)[2 * t], a1 = ((const float4*)sc)[2 * t + 1];
  float4 b0 = ((const float4*)sh)[2 * t], b1 = ((const float4*)sh)[2 * t + 1];
  float v[8];
  v[0] = fmaxf(fmaf(bf2f(z8[0]), a0.x, b0.x), 0.f);
  v[1] = fmaxf(fmaf(bf2f(z8[1]), a0.y, b0.y), 0.f);
  v[2] = fmaxf(fmaf(bf2f(z8[2]), a0.z, b0.z), 0.f);
  v[3] = fmaxf(fmaf(bf2f(z8[3]), a0.w, b0.w), 0.f);
  v[4] = fmaxf(fmaf(bf2f(z8[4]), a1.x, b1.x), 0.f);
  v[5] = fmaxf(fmaf(bf2f(z8[5]), a1.y, b1.y), 0.f);
  v[6] = fmaxf(fmaf(bf2f(z8[6]), a1.z, b1.z), 0.f);
  v[7] = fmaxf(fmaf(bf2f(z8[7]), a1.w, b1.w), 0.f);
  float ss = 0.f;
#pragma unroll
  for (int i = 0; i < 8; ++i) ss = fmaf(v[i], v[i], ss);
#pragma unroll
  for (int o = 32; o > 0; o >>= 1) ss += __shfl_down(ss, o, 64);
  if ((t & 63) == 0) red[t >> 6] = ss;
  __syncthreads();
  float n2 = red[0] + red[1] + red[2] + red[3];

  const float rsc = 0.31622776601683794f;  // sqrt(0.1)
  float fac;
  if (STAGE2) {
    float nn = sqrtf(n2);
    float vn = fmaxf(nn, 1e-8f);
    float tt = rsc * vn;
    float scl = tanhf(tt) / tt;
    float hn = scl * nn;
    float cn = fminf(fmaxf(hn, 1e-8f), 1.0f);
    float z = rsc * cn;
    fac = scl * (atanhf(z) / z);
  } else {
    fac = 0.f;
    if (n2 > 0.f) {
      float n = sqrtf(n2);
      float th = tanhf(rsc * n);
      float s = 0.9f * th / (rsc * n);
      float dn = fmaxf(s * n, 1e-8f);
      float z = rsc * dn;
      fac = -(atanhf(z) / z) * s;
    }
  }
  us8 o8;
#pragma unroll
  for (int i = 0; i < 8; ++i) o8[i] = f2bf(v[i] * fac);
  ((us8*)(Ab + (long)row * 2048))[t] = o8;
}

// -------- log_softmax over 1000 cols; sums the two split-K partials + bias --------
__global__ void __launch_bounds__(256) k_lsm(const float* __restrict__ Za,
                                             const float* __restrict__ Zb2,
                                             const float* __restrict__ b3,
                                             float* __restrict__ out) {
  __shared__ float red[4];
  int row = blockIdx.x, t = threadIdx.x;
  const float* za = Za + (long)row * 1024;
  const float* zb = Zb2 + (long)row * 1024;
  float v[4];
  float mx = -3.4e38f;
#pragma unroll
  for (int i = 0; i < 4; ++i) {
    int c = t + i * 256;
    v[i] = (c < 1000) ? (za[c] + zb[c] + b3[c]) : -3.4e38f;
    mx = fmaxf(mx, v[i]);
  }
#pragma unroll
  for (int o = 32; o > 0; o >>= 1) mx = fmaxf(mx, __shfl_down(mx, o, 64));
  if ((t & 63) == 0) red[t >> 6] = mx;
  __syncthreads();
  mx = fmaxf(fmaxf(red[0], red[1]), fmaxf(red[2], red[3]));
  __syncthreads();

  float se = 0.f;
#pragma unroll
  for (int i = 0; i < 4; ++i) {
    int c = t + i * 256;
    if (c < 1000) se += expf(v[i] - mx);
  }
#pragma unroll
  for (int o = 32; o > 0; o >>= 1) se += __shfl_down(se, o, 64);
  if ((t & 63) == 0) red[t >> 6] = se;
  __syncthreads();
  float s = red[0] + red[1] + red[2] + red[3];
  float ls = logf(s);
#pragma unroll
  for (int i = 0; i < 4; ++i) {
    int c = t + i * 256;
    if (c < 1000) out[(long)row * 1000 + c] = v[i] - mx - ls;
  }
}

extern "C" void kernel_launch(void* const* d_in, const int* in_sizes, int n_in,
                              void* d_out, int out_size, void* d_ws, size_t ws_size,
                              hipStream_t stream) {
  (void)in_sizes; (void)n_in; (void)out_size; (void)ws_size;
  const float* x   = (const float*)d_in[0];
  const float* W1  = (const float*)d_in[1];
  // d_in[2] = b1: exactly cancelled by BN (mean absorbs it)
  const float* g1  = (const float*)d_in[3];
  const float* be1 = (const float*)d_in[4];
  const float* W2  = (const float*)d_in[5];
  // d_in[6] = b2: cancelled by BN
  const float* g2  = (const float*)d_in[7];
  const float* be2 = (const float*)d_in[8];
  const float* W3  = (const float*)d_in[9];
  const float* b3  = (const float*)d_in[10];
  float* out = (float*)d_out;

  char* ws = (char*)d_ws;
  size_t off = 0;
  auto alloc = [&](size_t bytes) {
    void* p = ws + off;
    off += (bytes + 255) & ~(size_t)255;
    return p;
  };
  unsigned short* Xb  = (unsigned short*)alloc((size_t)8192 * 1024 * 2);
  unsigned short* W1b = (unsigned short*)alloc((size_t)2048 * 1024 * 2);
  unsigned short* W2b = (unsigned short*)alloc((size_t)2048 * 2048 * 2);
  unsigned short* W3b = (unsigned short*)alloc((size_t)1024 * 2048 * 2);
  unsigned short* Zb  = (unsigned short*)alloc((size_t)8192 * 2048 * 2);
  unsigned short* Ab  = (unsigned short*)alloc((size_t)8192 * 2048 * 2);
  float* Z3a          = (float*)alloc((size_t)8192 * 1024 * 4);
  float* P            = (float*)alloc((size_t)2 * 4096 * 4);   // P1 | P2, zeroed by k_prep
  float* SC           = (float*)alloc(2048 * 4);
  float* SH           = (float*)alloc(2048 * 4);
  float* P2 = P + 4096;
  // split-K slice-1 output aliases Zb: Zb is dead after k_fuse<true>, and
  // 8192*2048*2 B == 8192*1024*4 B == 32 MiB exactly. (Round-3 bug: aliasing onto
  // Xb..W2b was 28 MiB < 32 MiB and clobbered W3b mid-GEMM.)
  float* Z3b = (float*)Zb;

  // conversions + P zeroing
  k_prep<<<16392, 256, 0, stream>>>(x, W1, W2, W3, Xb, W1b, W2b, W3b, P);

  // layer 1: GEMM (+BN stats) -> bnfin -> fused hyperbolic
  k_gemm<true, true><<<dim3(16, 64), 256, 0, stream>>>(Xb, W1b, Zb, 1024, 1024, 1024, 2048, 2048, nullptr, P);
  k_bnfin<<<8, 256, 0, stream>>>(P, g1, be1, SC, SH);
  k_fuse<false><<<8192, 256, 0, stream>>>(Zb, SC, SH, Ab);

  // layer 2
  k_gemm<true, true><<<dim3(16, 64), 256, 0, stream>>>(Ab, W2b, Zb, 2048, 2048, 2048, 2048, 2048, nullptr, P2);
  k_bnfin<<<8, 256, 0, stream>>>(P2, g2, be2, SC, SH);
  k_fuse<true><<<8192, 256, 0, stream>>>(Zb, SC, SH, Ab);

  // layer 3: split-K=2 via two launches (K halves), partials summed in k_lsm
  k_gemm<false, false><<<dim3(8, 64), 256, 0, stream>>>(Ab, W3b, Z3a, 1024, 2048, 2048, 1024, 1024, nullptr, nullptr);
  k_gemm<false, false><<<dim3(8, 64), 256, 0, stream>>>(Ab + 1024, W3b + 1024, Z3b, 1024, 2048, 2048, 1024, 1024, nullptr, nullptr);
  k_lsm<<<8192, 256, 0, stream>>>(Z3a, Z3b, b3, out);
}

// Round 5
// 355.783 us; speedup vs baseline: 1.2667x; 1.0148x over previous
//
#include <hip/hip_runtime.h>

typedef __bf16 bf16x8 __attribute__((ext_vector_type(8)));
typedef float f32x16 __attribute__((ext_vector_type(16)));
typedef unsigned short us8 __attribute__((ext_vector_type(8)));

#define AS1 __attribute__((address_space(1)))
#define AS3 __attribute__((address_space(3)))

__device__ __forceinline__ unsigned short f2bf(float x) {
  unsigned int u = __float_as_uint(x);
  u += 0x7fffu + ((u >> 16) & 1u);   // RNE
  return (unsigned short)(u >> 16);
}
__device__ __forceinline__ float bf2f(unsigned short u) {
  return __uint_as_float(((unsigned int)u) << 16);
}
__device__ __forceinline__ void async_copy16(const void* g, void* l) {
  __builtin_amdgcn_global_load_lds((AS1 void*)(g), (AS3 void*)(l), 16, 0, 0);
}

// ------------- prep: all f32->bf16 conversions + P zeroing, one launch -------------
__global__ void __launch_bounds__(256) k_prep(const float* __restrict__ x,
                                              const float* __restrict__ W1,
                                              const float* __restrict__ W2,
                                              const float* __restrict__ W3,
                                              unsigned short* __restrict__ Xb,
                                              unsigned short* __restrict__ W1b,
                                              unsigned short* __restrict__ W2b,
                                              unsigned short* __restrict__ W3b,
                                              float* __restrict__ P) {
  const long n1 = 2097152, n2 = 524288, n3 = 1048576, n4 = 524288;
  long i = (long)blockIdx.x * 256 + threadIdx.x;   // float4 group index
  const float* s = nullptr;
  unsigned short* d = nullptr;
  long j = i;
  if (i < n1)                { s = x;  d = Xb; }
  else if ((j -= n1) < n2)   { s = W1; d = W1b; }
  else if ((j -= n2) < n3)   { s = W2; d = W2b; }
  else if ((j -= n3) < n4) {
    // W3: [1000,2048] -> padded [1024,2048], zero rows >= 1000
    ushort4 o;
    if ((j >> 9) < 1000) {
      float4 v = ((const float4*)W3)[j];
      o.x = f2bf(v.x); o.y = f2bf(v.y); o.z = f2bf(v.z); o.w = f2bf(v.w);
    } else { o.x = 0; o.y = 0; o.z = 0; o.w = 0; }
    ((ushort4*)W3b)[j] = o;
    return;
  } else {
    j -= n4;                                        // 0..2047 -> zero P (2 buffers)
    ((float4*)P)[j] = (float4){0.f, 0.f, 0.f, 0.f};
    return;
  }
  float4 v = ((const float4*)s)[j];
  ushort4 o;
  o.x = f2bf(v.x); o.y = f2bf(v.y); o.z = f2bf(v.z); o.w = f2bf(v.w);
  ((ushort4*)d)[j] = o;
}

// ---------------- GEMM: C[M,N] = A[M,K] * B[N,K]^T, bf16 in -----------------------
// 128x128 tile, BK=64, 32x32x16 MFMA core, XOR chunk swizzle, global_load_lds w=16.
// XCD swizzle: flat%8 = XCD (round-robin heuristic); each XCD gets an 8-m-block
// stripe (A-slice 4 MiB = one XCD L2) with all 128 of its blocks co-resident.
// blockIdx.z = K-split slice: A/B advance z*K, C goes to Cout (z=0) / Cout2 (z=1).
// STATS: per-column sum/sumsq of C atomically into P[0..2047]/P[2048..4095].
template <bool OUTBF16, bool STATS>
__global__ void __launch_bounds__(256) k_gemm(const unsigned short* __restrict__ A,
                                              const unsigned short* __restrict__ B,
                                              void* __restrict__ Cout,
                                              void* __restrict__ Cout2, int K,
                                              int lda, int ldb, int ldc,
                                              float* __restrict__ P) {
  __shared__ __align__(16) unsigned short lA[128 * 64];
  __shared__ __align__(16) unsigned short lB[128 * 64];
  const int tid = threadIdx.x;
  const int wave = tid >> 6;
  const int lane = tid & 63;

  // XCD-aware remap of (blockIdx.x, blockIdx.y) -> (nblk, mblk)
  const int f = blockIdx.x + gridDim.x * blockIdx.y;
  const int xcd = f & 7;
  const int fi = f >> 3;
  const int nblk = fi % gridDim.x;
  const int mblk = fi / gridDim.x + (gridDim.y >> 3) * xcd;
  const long m0 = (long)mblk * 128;
  const long n0 = (long)nblk * 128;
  const long koff = (long)blockIdx.z * K;

  // staging: wave covers rows [wave*32, wave*32+32), 4 rounds of 8 rows.
  // LDS slot (row, pos) holds global chunk (pos ^ (row&7)); lane l -> row l>>3, pos l&7.
  const int rsub = lane >> 3;                     // 0..7
  const int qg = ((lane & 7) ^ rsub) * 8;         // swizzled global chunk (halves)
  const unsigned short* gA = A + (m0 + wave * 32 + rsub) * (long)lda + koff + qg;
  const unsigned short* gB = B + (n0 + wave * 32 + rsub) * (long)ldb + koff + qg;
  unsigned short* lAw = lA + (wave * 32) * 64;
  unsigned short* lBw = lB + (wave * 32) * 64;

  const int wr = (wave >> 1) * 64;                // wave row offset in tile
  const int wc = (wave & 1) * 64;                 // wave col offset
  const int l31 = lane & 31;
  const int khalf = lane >> 5;                    // 0..1
  const int r7 = l31 & 7;                         // fragment row & 7 (swizzle key)

  f32x16 acc[2][2];
#pragma unroll
  for (int i = 0; i < 2; ++i)
#pragma unroll
    for (int j = 0; j < 2; ++j) acc[i][j] = (f32x16)(0.f);

  for (int k0 = 0; k0 < K; k0 += 64) {
#pragma unroll
    for (int r = 0; r < 4; ++r) {
      async_copy16(gA + (long)(r * 8) * lda + k0, lAw + r * 8 * 64);
      async_copy16(gB + (long)(r * 8) * ldb + k0, lBw + r * 8 * 64);
    }
    __syncthreads();

#pragma unroll
    for (int ks = 0; ks < 4; ++ks) {             // K-step of 16
      const int off = ((ks * 2 + khalf) ^ r7) * 8;
      bf16x8 af[2], bfr[2];
#pragma unroll
      for (int i = 0; i < 2; ++i)
        af[i] = *(const bf16x8*)&lA[(wr + i * 32 + l31) * 64 + off];
#pragma unroll
      for (int j = 0; j < 2; ++j)
        bfr[j] = *(const bf16x8*)&lB[(wc + j * 32 + l31) * 64 + off];
#pragma unroll
      for (int i = 0; i < 2; ++i)
#pragma unroll
        for (int j = 0; j < 2; ++j)
          acc[i][j] = __builtin_amdgcn_mfma_f32_32x32x16_bf16(af[i], bfr[j], acc[i][j], 0, 0, 0);
    }
    __syncthreads();
  }

  // C/D layout: col = lane&31, row = (reg&3) + 8*(reg>>2) + 4*(lane>>5)
  const int rbase = 4 * khalf;
  if (OUTBF16) {
    unsigned short* C = (unsigned short*)Cout;
#pragma unroll
    for (int i = 0; i < 2; ++i)
#pragma unroll
      for (int j = 0; j < 2; ++j) {
        long col = n0 + wc + j * 32 + l31;
#pragma unroll
        for (int reg = 0; reg < 16; ++reg) {
          long row = m0 + wr + i * 32 + (reg & 3) + 8 * (reg >> 2) + rbase;
          C[row * (long)ldc + col] = f2bf(acc[i][j][reg]);
        }
      }
  } else {
    float* C = (float*)(blockIdx.z ? Cout2 : Cout);
#pragma unroll
    for (int i = 0; i < 2; ++i)
#pragma unroll
      for (int j = 0; j < 2; ++j) {
        long col = n0 + wc + j * 32 + l31;
#pragma unroll
        for (int reg = 0; reg < 16; ++reg) {
          long row = m0 + wr + i * 32 + (reg & 3) + 8 * (reg >> 2) + rbase;
          C[row * (long)ldc + col] = acc[i][j][reg];
        }
      }
  }

  if (STATS) {
    float* sred = (float*)lA;    // reuse LDS (post final barrier)
    sred[tid] = 0.f;             // sum[0..127], sumsq[128..255]
    __syncthreads();
#pragma unroll
    for (int j = 0; j < 2; ++j) {
      float s = 0.f, s2 = 0.f;
#pragma unroll
      for (int i = 0; i < 2; ++i)
#pragma unroll
        for (int reg = 0; reg < 16; ++reg) {
          float v = acc[i][j][reg];
          s += v;
          s2 = fmaf(v, v, s2);
        }
      int cl = wc + j * 32 + l31;      // 0..127
      atomicAdd(&sred[cl], s);
      atomicAdd(&sred[128 + cl], s2);
    }
    __syncthreads();
    if (tid < 128) {
      atomicAdd(&P[n0 + tid], sred[tid]);
      atomicAdd(&P[2048 + n0 + tid], sred[128 + tid]);
    }
  }
}

// ------- fused BN-finalize + BN-apply + relu + row-norm + hyperbolic factor -------
// One wave per row (no block barriers). Each lane handles the 32 cols it touches:
// cols (lane+64c)*8..+7, c=0..3. Scale/shift computed per-lane from P/g/be.
// STAGE1: factor = -s * atanh(rsc*dn)/(rsc*dn), s = 0.9*tanh(rsc*n)/(rsc*n)
// STAGE2: factor = scl * atanh(rsc*cn)/(rsc*cn), scl = tanh(rsc*vn)/(rsc*vn)
template <bool STAGE2>
__global__ void __launch_bounds__(256) k_fuse(const unsigned short* __restrict__ Zb,
                                              const float* __restrict__ P,
                                              const float* __restrict__ g,
                                              const float* __restrict__ be,
                                              unsigned short* __restrict__ Ab) {
  const int t = threadIdx.x, wave = t >> 6, lane = t & 63;
  const long row = (long)blockIdx.x * 4 + wave;

  float sc[32], sh[32];
#pragma unroll
  for (int c = 0; c < 4; ++c) {
    int b4 = (lane + 64 * c) * 2;                 // float4 index of col base
    float4 s0 = ((const float4*)P)[b4],       s1 = ((const float4*)P)[b4 + 1];
    float4 q0 = ((const float4*)P)[512 + b4], q1 = ((const float4*)P)[512 + b4 + 1];
    float4 g0 = ((const float4*)g)[b4],       g1 = ((const float4*)g)[b4 + 1];
    float4 e0 = ((const float4*)be)[b4],      e1 = ((const float4*)be)[b4 + 1];
    float sm[8] = {s0.x, s0.y, s0.z, s0.w, s1.x, s1.y, s1.z, s1.w};
    float sq[8] = {q0.x, q0.y, q0.z, q0.w, q1.x, q1.y, q1.z, q1.w};
    float gg[8] = {g0.x, g0.y, g0.z, g0.w, g1.x, g1.y, g1.z, g1.w};
    float bb[8] = {e0.x, e0.y, e0.z, e0.w, e1.x, e1.y, e1.z, e1.w};
#pragma unroll
    for (int j = 0; j < 8; ++j) {
      float mean = sm[j] * (1.f / 8192.f);
      float var = sq[j] * (1.f / 8192.f) - mean * mean;
      float a = gg[j] * rsqrtf(var + 1e-5f);
      sc[c * 8 + j] = a;
      sh[c * 8 + j] = bb[j] - mean * a;
    }
  }

  const us8* zr = (const us8*)(Zb + row * 2048);
  float v[32];
  float ss = 0.f;
#pragma unroll
  for (int c = 0; c < 4; ++c) {
    us8 z8 = zr[lane + 64 * c];
#pragma unroll
    for (int j = 0; j < 8; ++j) {
      float xv = fmaxf(fmaf(bf2f(z8[j]), sc[c * 8 + j], sh[c * 8 + j]), 0.f);
      v[c * 8 + j] = xv;
      ss = fmaf(xv, xv, ss);
    }
  }
#pragma unroll
  for (int o = 32; o > 0; o >>= 1) ss += __shfl_xor(ss, o, 64);
  float n2 = ss;

  const float rsc = 0.31622776601683794f;  // sqrt(0.1)
  float fac;
  if (STAGE2) {
    float nn = sqrtf(n2);
    float vn = fmaxf(nn, 1e-8f);
    float tt = rsc * vn;
    float scl = tanhf(tt) / tt;
    float hn = scl * nn;
    float cn = fminf(fmaxf(hn, 1e-8f), 1.0f);
    float z = rsc * cn;
    fac = scl * (atanhf(z) / z);
  } else {
    fac = 0.f;
    if (n2 > 0.f) {
      float n = sqrtf(n2);
      float th = tanhf(rsc * n);
      float s = 0.9f * th / (rsc * n);
      float dn = fmaxf(s * n, 1e-8f);
      float z = rsc * dn;
      fac = -(atanhf(z) / z) * s;
    }
  }
  us8* dr = (us8*)(Ab + row * 2048);
#pragma unroll
  for (int c = 0; c < 4; ++c) {
    us8 o8;
#pragma unroll
    for (int j = 0; j < 8; ++j) o8[j] = f2bf(v[c * 8 + j] * fac);
    dr[lane + 64 * c] = o8;
  }
}

// -------- log_softmax over 1000 cols; one wave per row; sums split-K partials -----
__global__ void __launch_bounds__(256) k_lsm(const float* __restrict__ Za,
                                             const float* __restrict__ Zb2,
                                             const float* __restrict__ b3,
                                             float* __restrict__ out) {
  const int t = threadIdx.x, wave = t >> 6, lane = t & 63;
  const long row = (long)blockIdx.x * 4 + wave;
  const float* za = Za + row * 1024;
  const float* zb = Zb2 + row * 1024;
  float v[16];
  float mx = -3.4e38f;
#pragma unroll
  for (int c = 0; c < 16; ++c) {
    int col = lane + 64 * c;
    if (col < 1000) {
      v[c] = za[col] + zb[col] + b3[col];
      mx = fmaxf(mx, v[c]);
    } else v[c] = -3.4e38f;
  }
#pragma unroll
  for (int o = 32; o > 0; o >>= 1) mx = fmaxf(mx, __shfl_xor(mx, o, 64));

  float se = 0.f;
#pragma unroll
  for (int c = 0; c < 16; ++c) {
    int col = lane + 64 * c;
    if (col < 1000) se += expf(v[c] - mx);
  }
#pragma unroll
  for (int o = 32; o > 0; o >>= 1) se += __shfl_xor(se, o, 64);
  float ls = logf(se);

  float* orow = out + row * 1000;
#pragma unroll
  for (int c = 0; c < 16; ++c) {
    int col = lane + 64 * c;
    if (col < 1000) orow[col] = v[c] - mx - ls;
  }
}

extern "C" void kernel_launch(void* const* d_in, const int* in_sizes, int n_in,
                              void* d_out, int out_size, void* d_ws, size_t ws_size,
                              hipStream_t stream) {
  (void)in_sizes; (void)n_in; (void)out_size; (void)ws_size;
  const float* x   = (const float*)d_in[0];
  const float* W1  = (const float*)d_in[1];
  // d_in[2] = b1: exactly cancelled by BN (mean absorbs it)
  const float* g1  = (const float*)d_in[3];
  const float* be1 = (const float*)d_in[4];
  const float* W2  = (const float*)d_in[5];
  // d_in[6] = b2: cancelled by BN
  const float* g2  = (const float*)d_in[7];
  const float* be2 = (const float*)d_in[8];
  const float* W3  = (const float*)d_in[9];
  const float* b3  = (const float*)d_in[10];
  float* out = (float*)d_out;

  char* ws = (char*)d_ws;
  size_t off = 0;
  auto alloc = [&](size_t bytes) {
    void* p = ws + off;
    off += (bytes + 255) & ~(size_t)255;
    return p;
  };
  unsigned short* Xb  = (unsigned short*)alloc((size_t)8192 * 1024 * 2);
  unsigned short* W1b = (unsigned short*)alloc((size_t)2048 * 1024 * 2);
  unsigned short* W2b = (unsigned short*)alloc((size_t)2048 * 2048 * 2);
  unsigned short* W3b = (unsigned short*)alloc((size_t)1024 * 2048 * 2);
  unsigned short* Zb  = (unsigned short*)alloc((size_t)8192 * 2048 * 2);
  unsigned short* Ab  = (unsigned short*)alloc((size_t)8192 * 2048 * 2);
  float* Z3a          = (float*)alloc((size_t)8192 * 1024 * 4);
  float* P            = (float*)alloc((size_t)2 * 4096 * 4);   // P1 | P2, zeroed by k_prep
  float* P2 = P + 4096;
  // split-K slice-1 output aliases Zb (dead after k_fuse<true>; 32 MiB exactly)
  float* Z3b = (float*)Zb;

  // conversions + P zeroing
  k_prep<<<16392, 256, 0, stream>>>(x, W1, W2, W3, Xb, W1b, W2b, W3b, P);

  // layer 1: GEMM (+BN stats) -> fused BN-finalize+hyperbolic
  k_gemm<true, true><<<dim3(16, 64, 1), 256, 0, stream>>>(Xb, W1b, Zb, Zb, 1024, 1024, 1024, 2048, P);
  k_fuse<false><<<2048, 256, 0, stream>>>(Zb, P, g1, be1, Ab);

  // layer 2
  k_gemm<true, true><<<dim3(16, 64, 1), 256, 0, stream>>>(Ab, W2b, Zb, Zb, 2048, 2048, 2048, 2048, P2);
  k_fuse<true><<<2048, 256, 0, stream>>>(Zb, P2, g2, be2, Ab);

  // layer 3: split-K=2 in ONE launch (blockIdx.z), partials summed in k_lsm
  k_gemm<false, false><<<dim3(8, 64, 2), 256, 0, stream>>>(Ab, W3b, Z3a, Z3b, 1024, 2048, 2048, 1024, nullptr);
  k_lsm<<<2048, 256, 0, stream>>>(Z3a, Z3b, b3, out);
}

// Round 6
// 327.776 us; speedup vs baseline: 1.3749x; 1.0854x over previous
//
#include <hip/hip_runtime.h>

typedef __bf16 bf16x8 __attribute__((ext_vector_type(8)));
typedef float f32x16 __attribute__((ext_vector_type(16)));
typedef unsigned short us8 __attribute__((ext_vector_type(8)));

#define AS1 __attribute__((address_space(1)))
#define AS3 __attribute__((address_space(3)))

__device__ __forceinline__ unsigned short f2bf(float x) {
  unsigned int u = __float_as_uint(x);
  u += 0x7fffu + ((u >> 16) & 1u);   // RNE
  return (unsigned short)(u >> 16);
}
__device__ __forceinline__ float bf2f(unsigned short u) {
  return __uint_as_float(((unsigned int)u) << 16);
}
__device__ __forceinline__ void async_copy16(const void* g, void* l) {
  __builtin_amdgcn_global_load_lds((AS1 void*)(g), (AS3 void*)(l), 16, 0, 0);
}

// ------------- prep: all f32->bf16 conversions + P zeroing, one launch -------------
__global__ void __launch_bounds__(256) k_prep(const float* __restrict__ x,
                                              const float* __restrict__ W1,
                                              const float* __restrict__ W2,
                                              const float* __restrict__ W3,
                                              unsigned short* __restrict__ Xb,
                                              unsigned short* __restrict__ W1b,
                                              unsigned short* __restrict__ W2b,
                                              unsigned short* __restrict__ W3b,
                                              float* __restrict__ P) {
  const long n1 = 2097152, n2 = 524288, n3 = 1048576, n4 = 524288;
  long i = (long)blockIdx.x * 256 + threadIdx.x;   // float4 group index
  const float* s = nullptr;
  unsigned short* d = nullptr;
  long j = i;
  if (i < n1)                { s = x;  d = Xb; }
  else if ((j -= n1) < n2)   { s = W1; d = W1b; }
  else if ((j -= n2) < n3)   { s = W2; d = W2b; }
  else if ((j -= n3) < n4) {
    // W3: [1000,2048] -> padded [1024,2048], zero rows >= 1000
    ushort4 o;
    if ((j >> 9) < 1000) {
      float4 v = ((const float4*)W3)[j];
      o.x = f2bf(v.x); o.y = f2bf(v.y); o.z = f2bf(v.z); o.w = f2bf(v.w);
    } else { o.x = 0; o.y = 0; o.z = 0; o.w = 0; }
    ((ushort4*)W3b)[j] = o;
    return;
  } else {
    j -= n4;                                        // 0..2047 -> zero P (2 buffers)
    ((float4*)P)[j] = (float4){0.f, 0.f, 0.f, 0.f};
    return;
  }
  float4 v = ((const float4*)s)[j];
  ushort4 o;
  o.x = f2bf(v.x); o.y = f2bf(v.y); o.z = f2bf(v.z); o.w = f2bf(v.w);
  ((ushort4*)d)[j] = o;
}

// ---------------- GEMM: C[M,N] = A[M,K] * B[N,K]^T, bf16 in -----------------------
// 128(M)x256(N) tile, 4 waves, wave tile 64x128: af[2] x bfr[4] -> 8 MFMA per 6
// ds_read_b128 (FLOP/LDS-byte 28.4 vs 21.3 for 128^2 — LDS-read-bw is the binding
// pipe per r5 analysis). BK=64, 32x32x16 MFMA, XOR chunk swizzle, global_load_lds
// w=16 staging. 48 KB LDS, ~185 VGPR -> 2 blocks/CU.
// XCD swizzle: flat%8 = XCD; each XCD gets a contiguous m-stripe for A L2 reuse.
// blockIdx.z = K-split slice: A/B advance z*K, C goes to Cout (z=0) / Cout2 (z=1).
// STATS: per-column sum/sumsq of C atomically into P[0..2047]/P[2048..4095].
template <bool OUTBF16, bool STATS>
__global__ void __launch_bounds__(256, 2) k_gemm(const unsigned short* __restrict__ A,
                                                 const unsigned short* __restrict__ B,
                                                 void* __restrict__ Cout,
                                                 void* __restrict__ Cout2, int K,
                                                 int lda, int ldb, int ldc,
                                                 float* __restrict__ P) {
  __shared__ __align__(16) unsigned short lA[128 * 64];   // 16 KB
  __shared__ __align__(16) unsigned short lB[256 * 64];   // 32 KB
  const int tid = threadIdx.x;
  const int wave = tid >> 6;
  const int lane = tid & 63;

  // XCD-aware remap of (blockIdx.x, blockIdx.y) -> (nblk, mblk)
  const int f = blockIdx.x + gridDim.x * blockIdx.y;
  const int xcd = f & 7;
  const int fi = f >> 3;
  const int nblk = fi % gridDim.x;
  const int mblk = fi / gridDim.x + (gridDim.y >> 3) * xcd;
  const long m0 = (long)mblk * 128;
  const long n0 = (long)nblk * 256;
  const long koff = (long)blockIdx.z * K;

  // staging: A — wave covers rows [wave*32, +32), 4 rounds of 8; B — [wave*64, +64),
  // 8 rounds of 8. LDS slot (row,pos) holds global chunk (pos ^ (row&7)).
  const int rsub = lane >> 3;                     // 0..7
  const int qg = ((lane & 7) ^ rsub) * 8;         // swizzled global chunk (halves)
  const unsigned short* gA = A + (m0 + wave * 32 + rsub) * (long)lda + koff + qg;
  const unsigned short* gB = B + (n0 + wave * 64 + rsub) * (long)ldb + koff + qg;
  unsigned short* lAw = lA + (wave * 32) * 64;
  unsigned short* lBw = lB + (wave * 64) * 64;

  const int wr = (wave >> 1) * 64;                // wave row offset in tile (0,64)
  const int wc = (wave & 1) * 128;                // wave col offset (0,128)
  const int l31 = lane & 31;
  const int khalf = lane >> 5;                    // 0..1
  const int r7 = l31 & 7;                         // fragment row & 7 (swizzle key)

  f32x16 acc[2][4];
#pragma unroll
  for (int i = 0; i < 2; ++i)
#pragma unroll
    for (int j = 0; j < 4; ++j) acc[i][j] = (f32x16)(0.f);

  for (int k0 = 0; k0 < K; k0 += 64) {
#pragma unroll
    for (int r = 0; r < 4; ++r)
      async_copy16(gA + (long)(r * 8) * lda + k0, lAw + r * 8 * 64);
#pragma unroll
    for (int r = 0; r < 8; ++r)
      async_copy16(gB + (long)(r * 8) * ldb + k0, lBw + r * 8 * 64);
    __syncthreads();

#pragma unroll
    for (int ks = 0; ks < 4; ++ks) {             // K-step of 16
      const int off = ((ks * 2 + khalf) ^ r7) * 8;
      bf16x8 af[2], bfr[4];
#pragma unroll
      for (int i = 0; i < 2; ++i)
        af[i] = *(const bf16x8*)&lA[(wr + i * 32 + l31) * 64 + off];
#pragma unroll
      for (int j = 0; j < 4; ++j)
        bfr[j] = *(const bf16x8*)&lB[(wc + j * 32 + l31) * 64 + off];
#pragma unroll
      for (int i = 0; i < 2; ++i)
#pragma unroll
        for (int j = 0; j < 4; ++j)
          acc[i][j] = __builtin_amdgcn_mfma_f32_32x32x16_bf16(af[i], bfr[j], acc[i][j], 0, 0, 0);
    }
    __syncthreads();
  }

  // C/D layout: col = lane&31, row = (reg&3) + 8*(reg>>2) + 4*(lane>>5)
  const int rbase = 4 * khalf;
  if (OUTBF16) {
    unsigned short* C = (unsigned short*)Cout;
#pragma unroll
    for (int i = 0; i < 2; ++i)
#pragma unroll
      for (int j = 0; j < 4; ++j) {
        long col = n0 + wc + j * 32 + l31;
#pragma unroll
        for (int reg = 0; reg < 16; ++reg) {
          long row = m0 + wr + i * 32 + (reg & 3) + 8 * (reg >> 2) + rbase;
          C[row * (long)ldc + col] = f2bf(acc[i][j][reg]);
        }
      }
  } else {
    float* C = (float*)(blockIdx.z ? Cout2 : Cout);
#pragma unroll
    for (int i = 0; i < 2; ++i)
#pragma unroll
      for (int j = 0; j < 4; ++j) {
        long col = n0 + wc + j * 32 + l31;
#pragma unroll
        for (int reg = 0; reg < 16; ++reg) {
          long row = m0 + wr + i * 32 + (reg & 3) + 8 * (reg >> 2) + rbase;
          C[row * (long)ldc + col] = acc[i][j][reg];
        }
      }
  }

  if (STATS) {
    float* sred = (float*)lA;    // reuse LDS (post final barrier): 512 floats
    sred[tid] = 0.f;
    sred[256 + tid] = 0.f;       // sum[0..255], sumsq[256..511]
    __syncthreads();
#pragma unroll
    for (int j = 0; j < 4; ++j) {
      float s = 0.f, s2 = 0.f;
#pragma unroll
      for (int i = 0; i < 2; ++i)
#pragma unroll
        for (int reg = 0; reg < 16; ++reg) {
          float v = acc[i][j][reg];
          s += v;
          s2 = fmaf(v, v, s2);
        }
      int cl = wc + j * 32 + l31;      // 0..255
      atomicAdd(&sred[cl], s);
      atomicAdd(&sred[256 + cl], s2);
    }
    __syncthreads();
    atomicAdd(&P[n0 + tid], sred[tid]);
    atomicAdd(&P[2048 + n0 + tid], sred[256 + tid]);
  }
}

// ------- fused BN-finalize + BN-apply + relu + row-norm + hyperbolic factor -------
// One wave per row. Each lane handles cols (lane+64c)*8..+7, c=0..3; scale/shift
// computed per-lane from P/g/be (L2-hit redundant reads, ~2 us total).
template <bool STAGE2>
__global__ void __launch_bounds__(256) k_fuse(const unsigned short* __restrict__ Zb,
                                              const float* __restrict__ P,
                                              const float* __restrict__ g,
                                              const float* __restrict__ be,
                                              unsigned short* __restrict__ Ab) {
  const int t = threadIdx.x, wave = t >> 6, lane = t & 63;
  const long row = (long)blockIdx.x * 4 + wave;

  float sc[32], sh[32];
#pragma unroll
  for (int c = 0; c < 4; ++c) {
    int b4 = (lane + 64 * c) * 2;                 // float4 index of col base
    float4 s0 = ((const float4*)P)[b4],       s1 = ((const float4*)P)[b4 + 1];
    float4 q0 = ((const float4*)P)[512 + b4], q1 = ((const float4*)P)[512 + b4 + 1];
    float4 g0 = ((const float4*)g)[b4],       g1 = ((const float4*)g)[b4 + 1];
    float4 e0 = ((const float4*)be)[b4],      e1 = ((const float4*)be)[b4 + 1];
    float sm[8] = {s0.x, s0.y, s0.z, s0.w, s1.x, s1.y, s1.z, s1.w};
    float sq[8] = {q0.x, q0.y, q0.z, q0.w, q1.x, q1.y, q1.z, q1.w};
    float gg[8] = {g0.x, g0.y, g0.z, g0.w, g1.x, g1.y, g1.z, g1.w};
    float bb[8] = {e0.x, e0.y, e0.z, e0.w, e1.x, e1.y, e1.z, e1.w};
#pragma unroll
    for (int j = 0; j < 8; ++j) {
      float mean = sm[j] * (1.f / 8192.f);
      float var = sq[j] * (1.f / 8192.f) - mean * mean;
      float a = gg[j] * rsqrtf(var + 1e-5f);
      sc[c * 8 + j] = a;
      sh[c * 8 + j] = bb[j] - mean * a;
    }
  }

  const us8* zr = (const us8*)(Zb + row * 2048);
  float v[32];
  float ss = 0.f;
#pragma unroll
  for (int c = 0; c < 4; ++c) {
    us8 z8 = zr[lane + 64 * c];
#pragma unroll
    for (int j = 0; j < 8; ++j) {
      float xv = fmaxf(fmaf(bf2f(z8[j]), sc[c * 8 + j], sh[c * 8 + j]), 0.f);
      v[c * 8 + j] = xv;
      ss = fmaf(xv, xv, ss);
    }
  }
#pragma unroll
  for (int o = 32; o > 0; o >>= 1) ss += __shfl_xor(ss, o, 64);
  float n2 = ss;

  const float rsc = 0.31622776601683794f;  // sqrt(0.1)
  float fac;
  if (STAGE2) {
    float nn = sqrtf(n2);
    float vn = fmaxf(nn, 1e-8f);
    float tt = rsc * vn;
    float scl = tanhf(tt) / tt;
    float hn = scl * nn;
    float cn = fminf(fmaxf(hn, 1e-8f), 1.0f);
    float z = rsc * cn;
    fac = scl * (atanhf(z) / z);
  } else {
    fac = 0.f;
    if (n2 > 0.f) {
      float n = sqrtf(n2);
      float th = tanhf(rsc * n);
      float s = 0.9f * th / (rsc * n);
      float dn = fmaxf(s * n, 1e-8f);
      float z = rsc * dn;
      fac = -(atanhf(z) / z) * s;
    }
  }
  us8* dr = (us8*)(Ab + row * 2048);
#pragma unroll
  for (int c = 0; c < 4; ++c) {
    us8 o8;
#pragma unroll
    for (int j = 0; j < 8; ++j) o8[j] = f2bf(v[c * 8 + j] * fac);
    dr[lane + 64 * c] = o8;
  }
}

// -------- log_softmax over 1000 cols; one wave per row; sums split-K partials -----
__global__ void __launch_bounds__(256) k_lsm(const float* __restrict__ Za,
                                             const float* __restrict__ Zb2,
                                             const float* __restrict__ b3,
                                             float* __restrict__ out) {
  const int t = threadIdx.x, wave = t >> 6, lane = t & 63;
  const long row = (long)blockIdx.x * 4 + wave;
  const float* za = Za + row * 1024;
  const float* zb = Zb2 + row * 1024;
  float v[16];
  float mx = -3.4e38f;
#pragma unroll
  for (int c = 0; c < 16; ++c) {
    int col = lane + 64 * c;
    if (col < 1000) {
      v[c] = za[col] + zb[col] + b3[col];
      mx = fmaxf(mx, v[c]);
    } else v[c] = -3.4e38f;
  }
#pragma unroll
  for (int o = 32; o > 0; o >>= 1) mx = fmaxf(mx, __shfl_xor(mx, o, 64));

  float se = 0.f;
#pragma unroll
  for (int c = 0; c < 16; ++c) {
    int col = lane + 64 * c;
    if (col < 1000) se += expf(v[c] - mx);
  }
#pragma unroll
  for (int o = 32; o > 0; o >>= 1) se += __shfl_xor(se, o, 64);
  float ls = logf(se);

  float* orow = out + row * 1000;
#pragma unroll
  for (int c = 0; c < 16; ++c) {
    int col = lane + 64 * c;
    if (col < 1000) orow[col] = v[c] - mx - ls;
  }
}

extern "C" void kernel_launch(void* const* d_in, const int* in_sizes, int n_in,
                              void* d_out, int out_size, void* d_ws, size_t ws_size,
                              hipStream_t stream) {
  (void)in_sizes; (void)n_in; (void)out_size; (void)ws_size;
  const float* x   = (const float*)d_in[0];
  const float* W1  = (const float*)d_in[1];
  // d_in[2] = b1: exactly cancelled by BN (mean absorbs it)
  const float* g1  = (const float*)d_in[3];
  const float* be1 = (const float*)d_in[4];
  const float* W2  = (const float*)d_in[5];
  // d_in[6] = b2: cancelled by BN
  const float* g2  = (const float*)d_in[7];
  const float* be2 = (const float*)d_in[8];
  const float* W3  = (const float*)d_in[9];
  const float* b3  = (const float*)d_in[10];
  float* out = (float*)d_out;

  char* ws = (char*)d_ws;
  size_t off = 0;
  auto alloc = [&](size_t bytes) {
    void* p = ws + off;
    off += (bytes + 255) & ~(size_t)255;
    return p;
  };
  unsigned short* Xb  = (unsigned short*)alloc((size_t)8192 * 1024 * 2);
  unsigned short* W1b = (unsigned short*)alloc((size_t)2048 * 1024 * 2);
  unsigned short* W2b = (unsigned short*)alloc((size_t)2048 * 2048 * 2);
  unsigned short* W3b = (unsigned short*)alloc((size_t)1024 * 2048 * 2);
  unsigned short* Zb  = (unsigned short*)alloc((size_t)8192 * 2048 * 2);
  unsigned short* Ab  = (unsigned short*)alloc((size_t)8192 * 2048 * 2);
  float* Z3a          = (float*)alloc((size_t)8192 * 1024 * 4);
  float* P            = (float*)alloc((size_t)2 * 4096 * 4);   // P1 | P2, zeroed by k_prep
  float* P2 = P + 4096;
  // split-K slice-1 output aliases Zb (dead after k_fuse<true>; 32 MiB exactly)
  float* Z3b = (float*)Zb;

  // conversions + P zeroing
  k_prep<<<16392, 256, 0, stream>>>(x, W1, W2, W3, Xb, W1b, W2b, W3b, P);

  // layer 1: GEMM (+BN stats) -> fused BN-finalize+hyperbolic
  k_gemm<true, true><<<dim3(8, 64, 1), 256, 0, stream>>>(Xb, W1b, Zb, Zb, 1024, 1024, 1024, 2048, P);
  k_fuse<false><<<2048, 256, 0, stream>>>(Zb, P, g1, be1, Ab);

  // layer 2
  k_gemm<true, true><<<dim3(8, 64, 1), 256, 0, stream>>>(Ab, W2b, Zb, Zb, 2048, 2048, 2048, 2048, P2);
  k_fuse<true><<<2048, 256, 0, stream>>>(Zb, P2, g2, be2, Ab);

  // layer 3: split-K=2 in ONE launch (blockIdx.z), partials summed in k_lsm
  k_gemm<false, false><<<dim3(4, 64, 2), 256, 0, stream>>>(Ab, W3b, Z3a, Z3b, 1024, 2048, 2048, 1024, nullptr);
  k_lsm<<<2048, 256, 0, stream>>>(Z3a, Z3b, b3, out);
}